// Round 3
// baseline (787.338 us; speedup 1.0000x reference)
//
#include <hip/hip_runtime.h>

typedef unsigned short u16;
typedef u16 u16x8 __attribute__((ext_vector_type(8)));
typedef __bf16 bf16x8 __attribute__((ext_vector_type(8)));
typedef float f32x4 __attribute__((ext_vector_type(4)));

#define C_DIM 2048
#define NE 8
#define SA 72  // LDS stride in u16 (144 B = 16B-aligned, +4 banks/row -> 2-way max)

// ---- helpers ----
__device__ __forceinline__ unsigned pk2(float a, float b) {
  // round-half-up bf16 pair pack: 2 adds + 1 v_perm
  unsigned ua = __builtin_bit_cast(unsigned, a) + 0x8000u;
  unsigned ub = __builtin_bit_cast(unsigned, b) + 0x8000u;
  return __builtin_amdgcn_perm(ub, ua, 0x07060302);
}
__device__ __forceinline__ u16 f2bf(float f) {
  return (u16)((__builtin_bit_cast(unsigned, f) + 0x8000u) >> 16);
}
__device__ __forceinline__ uint4 pk8(f32x4 a, f32x4 b) {
  return make_uint4(pk2(a[0], a[1]), pk2(a[2], a[3]),
                    pk2(b[0], b[1]), pk2(b[2], b[3]));
}
__device__ __forceinline__ bf16x8 ldfrag(const u16* p) {
  union { u16x8 u; bf16x8 b; } x;
  x.u = *(const u16x8*)p;
  return x.b;
}

// ---- routing: scores, top-2 softmax, per-expert gather lists, sgate ----
__global__ __launch_bounds__(64) void routing_kernel(
    const float* __restrict__ x, const float* __restrict__ gw,
    const float* __restrict__ segw, int* __restrict__ counts,
    int* __restrict__ ptok, float* __restrict__ pw, float* __restrict__ sgate) {
  int t = blockIdx.x;
  int lane = threadIdx.x;
  const float* xr = x + (size_t)t * C_DIM;
  float s[NE];
#pragma unroll
  for (int e = 0; e < NE; e++) s[e] = 0.f;
  float sg = 0.f;
  for (int c = lane; c < C_DIM; c += 64) {
    float xv = xr[c];
#pragma unroll
    for (int e = 0; e < NE; e++) s[e] += xv * gw[e * C_DIM + c];
    sg += xv * segw[c];
  }
#pragma unroll
  for (int off = 32; off > 0; off >>= 1) {
#pragma unroll
    for (int e = 0; e < NE; e++) s[e] += __shfl_down(s[e], off);
    sg += __shfl_down(sg, off);
  }
  if (lane == 0) {
    int i0 = 0;
#pragma unroll
    for (int e = 1; e < NE; e++) if (s[e] > s[i0]) i0 = e;
    int i1 = (i0 == 0) ? 1 : 0;
#pragma unroll
    for (int e = 0; e < NE; e++) if (e != i0 && s[e] > s[i1]) i1 = e;
    float r = __expf(s[i1] - s[i0]);  // <= 1
    float w0 = 1.f / (1.f + r);
    float w1 = 1.f - w0;
    int s0 = atomicAdd(&counts[i0], 1);
    ptok[(i0 << 9) + s0] = t; pw[(i0 << 9) + s0] = w0;
    int s1 = atomicAdd(&counts[i1], 1);
    ptok[(i1 << 9) + s1] = t; pw[(i1 << 9) + s1] = w1;
    sgate[t] = 1.f / (1.f + __expf(-sg));
  }
}

// ---- fused gate+up SwiGLU GEMM ----
// Tile M=128 x N=16(gate)+16(up), BK=64, 256 thr = 4 waves, each wave a
// 32-row band computing BOTH gate and up (no cross-wave exchange).
// Expert mode: blockIdx -> (e = b&7 [XCD swizzle], mt = (b>>3)&3, nt = b>>5).
// Shared mode: (mt = b&3, nt = b>>2).
__global__ __launch_bounds__(256) void gateup_kernel(
    const float* __restrict__ x, const float* __restrict__ Wg,
    const float* __restrict__ Wu, u16* __restrict__ outb,
    const int* __restrict__ ptok, const int* __restrict__ counts,
    int N, int is_expert) {
  __shared__ u16 As[128 * SA];
  __shared__ u16 Bgs[16 * SA];
  __shared__ u16 Bus[16 * SA];

  int b = blockIdx.x;
  int e, mt, nt, cnt;
  const int* gth = nullptr;
  if (is_expert) {
    e = b & 7; mt = (b >> 3) & 3; nt = b >> 5;
    cnt = counts[e];
    if (mt * 128 >= cnt) return;
    gth = ptok + (e << 9);
  } else {
    e = 0; mt = b & 3; nt = b >> 2; cnt = 512;
  }
  const int K = C_DIM;
  int t = threadIdx.x;

  // A staging: row = t>>1 (0..127), half = t&1 (32 cols each)
  int arow = t >> 1, ahalf = t & 1;
  int aslot = mt * 128 + arow;
  int tok = gth ? ((aslot < cnt) ? gth[aslot] : gth[0]) : aslot;
  const float* ap = x + (size_t)tok * K + ahalf * 32;

  // W staging: wrow = t>>3 (0..31): rows 0-15 -> gate, 16-31 -> up
  int wrow = t >> 3, wseg = t & 7;
  int wmat = wrow >> 4, wloc = wrow & 15;
  const float* wp = (wmat ? Wu : Wg) + ((size_t)e * N + nt * 16 + wloc) * K + wseg * 8;
  u16* wlds = (wmat ? Bus : Bgs) + wloc * SA + wseg * 8;

  int lane = t & 63, wv = t >> 6;
  int quad = lane >> 4, l16 = lane & 15;

  f32x4 accg[2] = {}, accu[2] = {};
  f32x4 xr[8], wr[2];
#pragma unroll
  for (int s = 0; s < 8; s++) xr[s] = *(const f32x4*)(ap + s * 4);
  wr[0] = *(const f32x4*)(wp);
  wr[1] = *(const f32x4*)(wp + 4);

  int a_base = (wv * 32 + l16) * SA + quad * 8;
  int b_base = l16 * SA + quad * 8;
  int awr = arow * SA + ahalf * 32;

  const int NIT = K / 64;  // 32
  for (int kt = 0; kt < NIT; kt++) {
    __syncthreads();
#pragma unroll
    for (int s = 0; s < 4; s++)
      *(uint4*)&As[awr + s * 8] = pk8(xr[2 * s], xr[2 * s + 1]);
    *(uint4*)wlds = pk8(wr[0], wr[1]);
    __syncthreads();
    if (kt + 1 < NIT) {
      const float* a0 = ap + (kt + 1) * 64;
#pragma unroll
      for (int s = 0; s < 8; s++) xr[s] = *(const f32x4*)(a0 + s * 4);
      wr[0] = *(const f32x4*)(wp + (kt + 1) * 64);
      wr[1] = *(const f32x4*)(wp + (kt + 1) * 64 + 4);
    }
    bf16x8 a00 = ldfrag(&As[a_base]);
    bf16x8 a01 = ldfrag(&As[a_base + 32]);
    bf16x8 a10 = ldfrag(&As[a_base + 16 * SA]);
    bf16x8 a11 = ldfrag(&As[a_base + 16 * SA + 32]);
    bf16x8 g0 = ldfrag(&Bgs[b_base]);
    bf16x8 g1 = ldfrag(&Bgs[b_base + 32]);
    bf16x8 u0 = ldfrag(&Bus[b_base]);
    bf16x8 u1 = ldfrag(&Bus[b_base + 32]);
    accg[0] = __builtin_amdgcn_mfma_f32_16x16x32_bf16(a00, g0, accg[0], 0, 0, 0);
    accg[0] = __builtin_amdgcn_mfma_f32_16x16x32_bf16(a01, g1, accg[0], 0, 0, 0);
    accg[1] = __builtin_amdgcn_mfma_f32_16x16x32_bf16(a10, g0, accg[1], 0, 0, 0);
    accg[1] = __builtin_amdgcn_mfma_f32_16x16x32_bf16(a11, g1, accg[1], 0, 0, 0);
    accu[0] = __builtin_amdgcn_mfma_f32_16x16x32_bf16(a00, u0, accu[0], 0, 0, 0);
    accu[0] = __builtin_amdgcn_mfma_f32_16x16x32_bf16(a01, u1, accu[0], 0, 0, 0);
    accu[1] = __builtin_amdgcn_mfma_f32_16x16x32_bf16(a10, u0, accu[1], 0, 0, 0);
    accu[1] = __builtin_amdgcn_mfma_f32_16x16x32_bf16(a11, u1, accu[1], 0, 0, 0);
  }

  // epilogue: silu(g)*u per lane (C/D: row = quad*4+reg, col = l16)
  size_t obase = (size_t)e * 512 * N + (size_t)nt * 16 + l16;
#pragma unroll
  for (int i = 0; i < 2; i++)
#pragma unroll
    for (int g = 0; g < 4; g++) {
      int rloc = wv * 32 + i * 16 + quad * 4 + g;
      int slot = mt * 128 + rloc;
      if (slot < cnt) {
        float gv = accg[i][g], uv = accu[i][g];
        float sv = gv / (1.f + __expf(-gv));
        outb[obase + (size_t)slot * N] = f2bf(sv * uv);
      }
    }
}

// ---- down-proj GEMM: out += scale * (A_bf16 @ Wd^T), atomic combine ----
// Tile M=128 x N=32, BK=64, Ktile=1024 (16 iters), 256 thr = 4 waves.
// Expert: b -> (e = b&7, mt = (b>>3)&3, nt = b>>5), scale=pw, row=ptok.
// Shared: b -> (mt = b&3, ks = (b>>2)&1, nt = b>>3), scale=sgate, K-split 2.
__global__ __launch_bounds__(256) void down_kernel(
    const u16* __restrict__ Ab, const float* __restrict__ Wd,
    float* __restrict__ out, const int* __restrict__ ptok,
    const float* __restrict__ pw, const float* __restrict__ sgate,
    const int* __restrict__ counts, int AW, int is_expert) {
  __shared__ u16 As[128 * SA];
  __shared__ u16 Bs[32 * SA];

  int b = blockIdx.x;
  int e, mt, nt, ks, cnt;
  if (is_expert) {
    e = b & 7; mt = (b >> 3) & 3; nt = b >> 5; ks = 0;
    cnt = counts[e];
    if (mt * 128 >= cnt) return;
  } else {
    e = 0; mt = b & 3; ks = (b >> 2) & 1; nt = b >> 3; cnt = 512;
  }
  int t = threadIdx.x;
  int k0base = ks * 1024;

  // A staging: row = t>>1, half = t&1 -> 32 bf16 = 4 x uint4 per thread
  int arow = t >> 1, ahalf = t & 1;
  const u16* apr = Ab + ((size_t)e * 512 + mt * 128 + arow) * AW + k0base + ahalf * 32;
  // W staging: wrow = t>>3 (0..31), 2 f4
  int wrow = t >> 3, wseg = t & 7;
  const float* wp = Wd + ((size_t)(is_expert ? e * C_DIM : 0) + nt * 32 + wrow) * AW
                    + k0base + wseg * 8;

  int lane = t & 63, wv = t >> 6;
  int quad = lane >> 4, l16 = lane & 15;

  f32x4 acc[2][2] = {};
  uint4 axr[4]; f32x4 wr[2];
#pragma unroll
  for (int s = 0; s < 4; s++) axr[s] = *(const uint4*)(apr + s * 8);
  wr[0] = *(const f32x4*)(wp);
  wr[1] = *(const f32x4*)(wp + 4);

  int a_base = (wv * 32 + l16) * SA + quad * 8;
  int b_base = l16 * SA + quad * 8;
  int awr = arow * SA + ahalf * 32;
  int bwr = wrow * SA + wseg * 8;

  const int NIT = 16;  // 1024 / 64
  for (int kt = 0; kt < NIT; kt++) {
    __syncthreads();
#pragma unroll
    for (int s = 0; s < 4; s++) *(uint4*)&As[awr + s * 8] = axr[s];
    *(uint4*)&Bs[bwr] = pk8(wr[0], wr[1]);
    __syncthreads();
    if (kt + 1 < NIT) {
      const u16* a0 = apr + (kt + 1) * 64;
#pragma unroll
      for (int s = 0; s < 4; s++) axr[s] = *(const uint4*)(a0 + s * 8);
      wr[0] = *(const f32x4*)(wp + (kt + 1) * 64);
      wr[1] = *(const f32x4*)(wp + (kt + 1) * 64 + 4);
    }
    bf16x8 a00 = ldfrag(&As[a_base]);
    bf16x8 a01 = ldfrag(&As[a_base + 32]);
    bf16x8 a10 = ldfrag(&As[a_base + 16 * SA]);
    bf16x8 a11 = ldfrag(&As[a_base + 16 * SA + 32]);
    bf16x8 b00 = ldfrag(&Bs[b_base]);
    bf16x8 b01 = ldfrag(&Bs[b_base + 32]);
    bf16x8 b10 = ldfrag(&Bs[b_base + 16 * SA]);
    bf16x8 b11 = ldfrag(&Bs[b_base + 16 * SA + 32]);
    acc[0][0] = __builtin_amdgcn_mfma_f32_16x16x32_bf16(a00, b00, acc[0][0], 0, 0, 0);
    acc[0][0] = __builtin_amdgcn_mfma_f32_16x16x32_bf16(a01, b01, acc[0][0], 0, 0, 0);
    acc[0][1] = __builtin_amdgcn_mfma_f32_16x16x32_bf16(a00, b10, acc[0][1], 0, 0, 0);
    acc[0][1] = __builtin_amdgcn_mfma_f32_16x16x32_bf16(a01, b11, acc[0][1], 0, 0, 0);
    acc[1][0] = __builtin_amdgcn_mfma_f32_16x16x32_bf16(a10, b00, acc[1][0], 0, 0, 0);
    acc[1][0] = __builtin_amdgcn_mfma_f32_16x16x32_bf16(a11, b01, acc[1][0], 0, 0, 0);
    acc[1][1] = __builtin_amdgcn_mfma_f32_16x16x32_bf16(a10, b10, acc[1][1], 0, 0, 0);
    acc[1][1] = __builtin_amdgcn_mfma_f32_16x16x32_bf16(a11, b11, acc[1][1], 0, 0, 0);
  }

#pragma unroll
  for (int i = 0; i < 2; i++)
#pragma unroll
    for (int j = 0; j < 2; j++)
#pragma unroll
      for (int g = 0; g < 4; g++) {
        int rloc = wv * 32 + i * 16 + quad * 4 + g;
        int col = nt * 32 + j * 16 + l16;
        float v = acc[i][j][g];
        if (is_expert) {
          int slot = mt * 128 + rloc;
          if (slot < cnt) {
            int tok = ptok[(e << 9) + slot];
            float w = pw[(e << 9) + slot];
            atomicAdd(&out[(size_t)tok * C_DIM + col], w * v);
          }
        } else {
          int row = mt * 128 + rloc;
          atomicAdd(&out[(size_t)row * C_DIM + col], sgate[row] * v);
        }
      }
}

extern "C" void kernel_launch(void* const* d_in, const int* in_sizes, int n_in,
                              void* d_out, int out_size, void* d_ws, size_t ws_size,
                              hipStream_t stream) {
  const float* x = (const float*)d_in[0];
  const float* gate_w = (const float*)d_in[1];
  const float* w_gate = (const float*)d_in[2];
  const float* w_up = (const float*)d_in[3];
  const float* w_down = (const float*)d_in[4];
  const float* sh_gate = (const float*)d_in[5];
  const float* sh_up = (const float*)d_in[6];
  const float* sh_down = (const float*)d_in[7];
  const float* se_gate_w = (const float*)d_in[8];
  float* out = (float*)d_out;

  char* ws = (char*)d_ws;
  int* counts = (int*)(ws + 0);                 // 32 B
  int* ptok = (int*)(ws + 1024);                // 16 KB
  float* pw = (float*)(ws + 1024 + 16384);      // 16 KB
  float* sg = (float*)(ws + 1024 + 32768);      // 2 KB
  u16* hbuf = (u16*)(ws + 65536);               // 8*512*1024 bf16 = 8 MB
  u16* hs = (u16*)(ws + 65536 + 8388608);       // 512*2048 bf16 = 2 MB

  hipMemsetAsync(counts, 0, 32, stream);
  hipMemsetAsync(out, 0, (size_t)out_size * sizeof(float), stream);
  routing_kernel<<<512, 64, 0, stream>>>(x, gate_w, se_gate_w, counts, ptok, pw, sg);

  // expert gate+up: 8e x 4mt x 64nt = 2048 blocks (~512 live, XCD-pinned by e)
  gateup_kernel<<<2048, 256, 0, stream>>>(x, w_gate, w_up, hbuf, ptok, counts, 1024, 1);
  // shared gate+up: 4mt x 128nt = 512 blocks
  gateup_kernel<<<512, 256, 0, stream>>>(x, sh_gate, sh_up, hs, nullptr, nullptr, 2048, 0);
  // shared down (K-split 2, atomic): 4mt x 2ks x 64nt = 512 blocks
  down_kernel<<<512, 256, 0, stream>>>(hs, sh_down, out, nullptr, nullptr, sg, nullptr, 2048, 0);
  // expert down: 8e x 4mt x 64nt = 2048 blocks (~512 live)
  down_kernel<<<2048, 256, 0, stream>>>(hbuf, w_down, out, ptok, pw, nullptr, counts, 1024, 1);
}

// Round 4
// 536.821 us; speedup vs baseline: 1.4667x; 1.4667x over previous
//
#include <hip/hip_runtime.h>

typedef unsigned short u16;
typedef u16 u16x8 __attribute__((ext_vector_type(8)));
typedef __bf16 bf16x8 __attribute__((ext_vector_type(8)));
typedef float f32x4 __attribute__((ext_vector_type(4)));

#define NE 8
#define SA 72  // LDS row stride in u16

// ---- helpers ----
__device__ __forceinline__ unsigned pk2(float a, float b) {
  unsigned ua = __builtin_bit_cast(unsigned, a) + 0x8000u;
  unsigned ub = __builtin_bit_cast(unsigned, b) + 0x8000u;
  return __builtin_amdgcn_perm(ub, ua, 0x07060302);
}
__device__ __forceinline__ u16 f2bf(float f) {
  return (u16)((__builtin_bit_cast(unsigned, f) + 0x8000u) >> 16);
}
__device__ __forceinline__ uint4 pk8(f32x4 a, f32x4 b) {
  return make_uint4(pk2(a[0], a[1]), pk2(a[2], a[3]),
                    pk2(b[0], b[1]), pk2(b[2], b[3]));
}
__device__ __forceinline__ bf16x8 ldfrag(const u16* p) {
  union { u16x8 u; bf16x8 b; } x;
  x.u = *(const u16x8*)p;
  return x.b;
}

// ---- routing ----
__global__ __launch_bounds__(64) void routing_kernel(
    const float* __restrict__ x, const float* __restrict__ gw,
    const float* __restrict__ segw, int* __restrict__ counts,
    int* __restrict__ ptok, float* __restrict__ pw, float* __restrict__ sgate) {
  int t = blockIdx.x;
  int lane = threadIdx.x;
  const float* xr = x + (size_t)t * 2048;
  float s[NE];
#pragma unroll
  for (int e = 0; e < NE; e++) s[e] = 0.f;
  float sg = 0.f;
  for (int c = lane; c < 2048; c += 64) {
    float xv = xr[c];
#pragma unroll
    for (int e = 0; e < NE; e++) s[e] += xv * gw[e * 2048 + c];
    sg += xv * segw[c];
  }
#pragma unroll
  for (int off = 32; off > 0; off >>= 1) {
#pragma unroll
    for (int e = 0; e < NE; e++) s[e] += __shfl_down(s[e], off);
    sg += __shfl_down(sg, off);
  }
  if (lane == 0) {
    int i0 = 0;
#pragma unroll
    for (int e = 1; e < NE; e++) if (s[e] > s[i0]) i0 = e;
    int i1 = (i0 == 0) ? 1 : 0;
#pragma unroll
    for (int e = 0; e < NE; e++) if (e != i0 && s[e] > s[i1]) i1 = e;
    float r = __expf(s[i1] - s[i0]);
    float w0 = 1.f / (1.f + r);
    float w1 = 1.f - w0;
    int s0 = atomicAdd(&counts[i0], 1);
    ptok[(i0 << 9) + s0] = t; pw[(i0 << 9) + s0] = w0;
    int s1 = atomicAdd(&counts[i1], 1);
    ptok[(i1 << 9) + s1] = t; pw[(i1 << 9) + s1] = w1;
    sgate[t] = 1.f / (1.f + __expf(-sg));
  }
}

// ---- prep: x fp32 -> bf16 once (2 MB, per-XCD L2 resident) ----
__global__ __launch_bounds__(256) void prep_kernel(
    const float* __restrict__ x, u16* __restrict__ xb) {
  int i = (blockIdx.x * 256 + threadIdx.x) * 32;
  const float* p = x + i;
  u16* o = xb + i;
#pragma unroll
  for (int s = 0; s < 4; s++) {
    f32x4 a = *(const f32x4*)(p + s * 8);
    f32x4 b = *(const f32x4*)(p + s * 8 + 4);
    *(uint4*)(o + s * 8) = pk8(a, b);
  }
}

// ---- gateup: M=128 x (64 gate + 64 up), BK=64, silu fused ----
// b<512: expert (e=b&7, j=(b>>3)&15, mt=b>>7); else shared (j=bs&31, mt=bs>>5).
__global__ __launch_bounds__(256) void gateup_kernel(
    const u16* __restrict__ xb, const float* __restrict__ Wg,
    const float* __restrict__ Wu, const float* __restrict__ SWg,
    const float* __restrict__ SWu, u16* __restrict__ hbuf,
    u16* __restrict__ hs, const int* __restrict__ ptok,
    const int* __restrict__ counts) {
  __shared__ u16 As[128 * SA];
  __shared__ u16 Bs[128 * SA];

  int b = blockIdx.x;
  int t = threadIdx.x;
  int is_ex = (b < 512);
  int e = 0, j, mt, cnt;
  const float *gW, *uW;
  if (is_ex) {
    e = b & 7; j = (b >> 3) & 15; mt = b >> 7;
    cnt = counts[e];
    if (mt * 128 >= cnt) return;
    gW = Wg + (size_t)(e * 1024 + j * 64) * 2048;
    uW = Wu + (size_t)(e * 1024 + j * 64) * 2048;
  } else {
    int bs = b - 512; j = bs & 31; mt = bs >> 5; cnt = 512;
    gW = SWg + (size_t)(j * 64) * 2048;
    uW = SWu + (size_t)(j * 64) * 2048;
  }

  // A staging: arow 0..127, half 32 bf16 each (64 B/thread/iter)
  int arow = t >> 1, ahalf = t & 1;
  int aslot = mt * 128 + arow;
  int tok = is_ex ? ((aslot < cnt) ? ptok[(e << 9) + aslot] : 0) : aslot;
  const u16* ap = xb + (size_t)tok * 2048 + ahalf * 32;

  // B staging: wrow 0..127 (0-63 gate, 64-127 up), half 32 fp32 (128 B/thread/iter)
  int wrow = t >> 1, whalf = t & 1;
  const float* wp = ((wrow < 64) ? (gW + (size_t)wrow * 2048)
                                 : (uW + (size_t)(wrow - 64) * 2048)) + whalf * 32;

  int lane = t & 63, wv = t >> 6;
  int quad = lane >> 4, l16 = lane & 15;
  int mw = wv & 1, nw = wv >> 1;

  f32x4 accg[4][2] = {}, accu[4][2] = {};
  uint4 apre[4]; f32x4 bpre[8];
#pragma unroll
  for (int s = 0; s < 4; s++) apre[s] = *(const uint4*)(ap + s * 8);
#pragma unroll
  for (int s = 0; s < 8; s++) bpre[s] = *(const f32x4*)(wp + s * 4);

  int awr = arow * SA + ahalf * 32;
  int bwr = wrow * SA + whalf * 32;

  const int NIT = 32;  // K=2048 / 64
  for (int kt = 0; kt < NIT; kt++) {
    __syncthreads();
#pragma unroll
    for (int s = 0; s < 4; s++) *(uint4*)&As[awr + s * 8] = apre[s];
#pragma unroll
    for (int s = 0; s < 4; s++) *(uint4*)&Bs[bwr + s * 8] = pk8(bpre[2 * s], bpre[2 * s + 1]);
    __syncthreads();
    if (kt + 1 < NIT) {
      const u16* a0 = ap + (kt + 1) * 64;
      const float* w0 = wp + (kt + 1) * 64;
#pragma unroll
      for (int s = 0; s < 4; s++) apre[s] = *(const uint4*)(a0 + s * 8);
#pragma unroll
      for (int s = 0; s < 8; s++) bpre[s] = *(const f32x4*)(w0 + s * 4);
    }
#pragma unroll
    for (int k2 = 0; k2 < 2; k2++) {
      bf16x8 af[4];
#pragma unroll
      for (int im = 0; im < 4; im++)
        af[im] = ldfrag(&As[(mw * 64 + im * 16 + l16) * SA + k2 * 32 + quad * 8]);
#pragma unroll
      for (int inn = 0; inn < 2; inn++) {
        bf16x8 bg = ldfrag(&Bs[(nw * 32 + inn * 16 + l16) * SA + k2 * 32 + quad * 8]);
        bf16x8 bu = ldfrag(&Bs[(64 + nw * 32 + inn * 16 + l16) * SA + k2 * 32 + quad * 8]);
#pragma unroll
        for (int im = 0; im < 4; im++) {
          accg[im][inn] = __builtin_amdgcn_mfma_f32_16x16x32_bf16(af[im], bg, accg[im][inn], 0, 0, 0);
          accu[im][inn] = __builtin_amdgcn_mfma_f32_16x16x32_bf16(af[im], bu, accu[im][inn], 0, 0, 0);
        }
      }
    }
  }

  // epilogue: h = silu(g)*u
#pragma unroll
  for (int im = 0; im < 4; im++)
#pragma unroll
    for (int inn = 0; inn < 2; inn++)
#pragma unroll
      for (int g = 0; g < 4; g++) {
        int rloc = mw * 64 + im * 16 + quad * 4 + g;
        int slot = mt * 128 + rloc;
        if (slot < cnt) {
          float gv = accg[im][inn][g], uv = accu[im][inn][g];
          float h = gv / (1.f + __expf(-gv)) * uv;
          int col = j * 64 + nw * 32 + inn * 16 + l16;
          if (is_ex) hbuf[((size_t)e * 512 + slot) * 1024 + col] = f2bf(h);
          else       hs[(size_t)slot * 2048 + col] = f2bf(h);
        }
      }
}

// ---- down: M=128 x N=128, BK=64, atomic combine into out ----
// b<512: expert (e=b&7, nt=(b>>3)&15, mt=b>>7), K=1024.
// b>=512: shared (nt=bs&15, mt=bs>>4), K=2048.
__global__ __launch_bounds__(256) void down_kernel(
    const u16* __restrict__ hbuf, const u16* __restrict__ hs,
    const float* __restrict__ Wd, const float* __restrict__ SWd,
    float* __restrict__ out, const int* __restrict__ ptok,
    const float* __restrict__ pw, const float* __restrict__ sgate,
    const int* __restrict__ counts) {
  __shared__ u16 As[128 * SA];
  __shared__ u16 Bs[128 * SA];

  int b = blockIdx.x;
  int t = threadIdx.x;
  int is_ex = (b < 512);
  int e = 0, nt, mt, cnt, K;
  const u16* abase;
  const float* wbase;
  if (is_ex) {
    e = b & 7; nt = (b >> 3) & 15; mt = b >> 7;
    cnt = counts[e];
    if (mt * 128 >= cnt) return;
    K = 1024;
    abase = hbuf + ((size_t)e * 512 + mt * 128) * 1024;
    wbase = Wd + (size_t)(e * 2048 + nt * 128) * 1024;
  } else {
    int bs = b - 512; nt = bs & 15; mt = bs >> 4; cnt = 512;
    K = 2048;
    abase = hs + (size_t)(mt * 128) * 2048;
    wbase = SWd + (size_t)(nt * 128) * 2048;
  }

  int arow = t >> 1, ahalf = t & 1;
  const u16* ap = abase + (size_t)arow * K + ahalf * 32;
  int wrow = t >> 1, whalf = t & 1;
  const float* wp = wbase + (size_t)wrow * K + whalf * 32;

  int lane = t & 63, wv = t >> 6;
  int quad = lane >> 4, l16 = lane & 15;
  int mw = wv & 1, nw = wv >> 1;

  f32x4 acc[4][4] = {};
  uint4 apre[4]; f32x4 bpre[8];
#pragma unroll
  for (int s = 0; s < 4; s++) apre[s] = *(const uint4*)(ap + s * 8);
#pragma unroll
  for (int s = 0; s < 8; s++) bpre[s] = *(const f32x4*)(wp + s * 4);

  int awr = arow * SA + ahalf * 32;
  int bwr = wrow * SA + whalf * 32;

  const int NIT = K >> 6;  // 16 or 32
  for (int kt = 0; kt < NIT; kt++) {
    __syncthreads();
#pragma unroll
    for (int s = 0; s < 4; s++) *(uint4*)&As[awr + s * 8] = apre[s];
#pragma unroll
    for (int s = 0; s < 4; s++) *(uint4*)&Bs[bwr + s * 8] = pk8(bpre[2 * s], bpre[2 * s + 1]);
    __syncthreads();
    if (kt + 1 < NIT) {
      const u16* a0 = ap + (kt + 1) * 64;
      const float* w0 = wp + (kt + 1) * 64;
#pragma unroll
      for (int s = 0; s < 4; s++) apre[s] = *(const uint4*)(a0 + s * 8);
#pragma unroll
      for (int s = 0; s < 8; s++) bpre[s] = *(const f32x4*)(w0 + s * 4);
    }
#pragma unroll
    for (int k2 = 0; k2 < 2; k2++) {
      bf16x8 af[4];
#pragma unroll
      for (int im = 0; im < 4; im++)
        af[im] = ldfrag(&As[(mw * 64 + im * 16 + l16) * SA + k2 * 32 + quad * 8]);
#pragma unroll
      for (int inn = 0; inn < 4; inn++) {
        bf16x8 bf = ldfrag(&Bs[(nw * 64 + inn * 16 + l16) * SA + k2 * 32 + quad * 8]);
#pragma unroll
        for (int im = 0; im < 4; im++)
          acc[im][inn] = __builtin_amdgcn_mfma_f32_16x16x32_bf16(af[im], bf, acc[im][inn], 0, 0, 0);
      }
    }
  }

#pragma unroll
  for (int im = 0; im < 4; im++)
#pragma unroll
    for (int inn = 0; inn < 4; inn++)
#pragma unroll
      for (int g = 0; g < 4; g++) {
        int rloc = mw * 64 + im * 16 + quad * 4 + g;
        int col = nt * 128 + nw * 64 + inn * 16 + l16;
        float v = acc[im][inn][g];
        if (is_ex) {
          int slot = mt * 128 + rloc;
          if (slot < cnt) {
            int tok = ptok[(e << 9) + slot];
            atomicAdd(&out[(size_t)tok * 2048 + col], pw[(e << 9) + slot] * v);
          }
        } else {
          int row = mt * 128 + rloc;
          atomicAdd(&out[(size_t)row * 2048 + col], sgate[row] * v);
        }
      }
}

extern "C" void kernel_launch(void* const* d_in, const int* in_sizes, int n_in,
                              void* d_out, int out_size, void* d_ws, size_t ws_size,
                              hipStream_t stream) {
  const float* x = (const float*)d_in[0];
  const float* gate_w = (const float*)d_in[1];
  const float* w_gate = (const float*)d_in[2];
  const float* w_up = (const float*)d_in[3];
  const float* w_down = (const float*)d_in[4];
  const float* sh_gate = (const float*)d_in[5];
  const float* sh_up = (const float*)d_in[6];
  const float* sh_down = (const float*)d_in[7];
  const float* se_gate_w = (const float*)d_in[8];
  float* out = (float*)d_out;

  char* ws = (char*)d_ws;
  int* counts = (int*)(ws + 0);                       // 32 B
  int* ptok = (int*)(ws + 1024);                      // 16 KB
  float* pw = (float*)(ws + 1024 + 16384);            // 16 KB
  float* sg = (float*)(ws + 1024 + 32768);            // 2 KB
  u16* xb = (u16*)(ws + 65536);                       // 512*2048 bf16 = 2 MB
  u16* hbuf = (u16*)(ws + 65536 + (2u << 20));        // 8*512*1024 bf16 = 8 MB
  u16* hs = (u16*)(ws + 65536 + (10u << 20));         // 512*2048 bf16 = 2 MB

  hipMemsetAsync(counts, 0, 32, stream);
  hipMemsetAsync(out, 0, (size_t)out_size * sizeof(float), stream);
  routing_kernel<<<512, 64, 0, stream>>>(x, gate_w, se_gate_w, counts, ptok, pw, sg);
  prep_kernel<<<128, 256, 0, stream>>>(x, xb);
  // gateup: expert 8e*16j*4mt = 512 (live ~128) + shared 32j*4mt = 128
  gateup_kernel<<<640, 256, 0, stream>>>(xb, w_gate, w_up, sh_gate, sh_up,
                                         hbuf, hs, ptok, counts);
  // down: expert 8e*16nt*4mt = 512 (live ~128) + shared 16nt*4mt = 64
  down_kernel<<<576, 256, 0, stream>>>(hbuf, hs, w_down, sh_down, out,
                                       ptok, pw, sg, counts);
}